// Round 2
// baseline (5384.004 us; speedup 1.0000x reference)
//
#include <hip/hip_runtime.h>
#include <hip/hip_bf16.h>

#define DF 200   // feature dim D
#define HC 100   // H*C
#define NH 2     // heads
#define CD 50    // channels per head
#define NG 512   // num graphs

__device__ __forceinline__ float eluf(float x){ return x>0.f ? x : expm1f(x); }

// ---------------- elementwise elu (f32 -> f32) ----------------
__global__ void k_elu(const float* __restrict__ in, float* __restrict__ out, int n){
  int i = blockIdx.x*blockDim.x + threadIdx.x;
  if(i<n) out[i] = eluf(in[i]);
}

// ---------------- V[k][h] = sum_c W[k][h*50+c]*a[h][c]  (fused attention vec) ----------------
__global__ void k_makeV(const float* __restrict__ W, const float* __restrict__ a, float* __restrict__ V){
  int i = blockIdx.x*blockDim.x + threadIdx.x;
  if(i >= DF*NH) return;
  int k = i>>1, h = i&1;
  float s = 0.f;
  #pragma unroll
  for(int c=0;c<CD;c++) s += W[k*HC + h*CD + c] * a[h*CD + c];
  V[k*2+h] = s;
}

// pack two [200] f32 vectors into V[200][2] (for SAG Wrel|Wroot)
__global__ void k_pack2(const float* __restrict__ a, const float* __restrict__ c, float* __restrict__ V){
  int k = blockIdx.x*blockDim.x + threadIdx.x;
  if(k<DF){ V[k*2] = a[k]; V[k*2+1] = c[k]; }
}

// ---------------- al[n][0..1] = X[n,:] @ V[200,2]  (one wave per node) ----------------
__global__ void k_gemv2(const float* __restrict__ X, const float* __restrict__ V,
                        float* __restrict__ al, int N){
  int n = blockIdx.x; if(n>=N) return;
  int lane = threadIdx.x; // blockDim = 64
  float a0=0.f, a1=0.f;
  const float* xr = X + (size_t)n*DF;
  for(int k=lane;k<DF;k+=64){
    float x = xr[k];
    a0 += x*V[k*2]; a1 += x*V[k*2+1];
  }
  for(int o=32;o;o>>=1){ a0 += __shfl_down(a0,o); a1 += __shfl_down(a1,o); }
  if(lane==0){ al[n*2]=a0; al[n*2+1]=a1; }
}

// ---------------- out[N,100] = X[N,200] @ W(f32)[200,100] ; 4 cols per thread ----------------
__global__ void k_gemm(const float* __restrict__ X, const float* __restrict__ W,
                       float* __restrict__ out, int N){
  int i = blockIdx.x*blockDim.x + threadIdx.x;
  int total = N*25;
  if(i>=total) return;
  int n = i/25, jg = (i%25)*4;
  const float* xr = X + (size_t)n*DF;
  float a0=0,a1=0,a2=0,a3=0;
  for(int k=0;k<DF;k++){
    float x = xr[k];
    float4 w = *(const float4*)(W + k*HC + jg);   // 16B-aligned: k*100+jg ≡ 0 mod 4
    a0 += x*w.x; a1 += x*w.y; a2 += x*w.z; a3 += x*w.w;
  }
  float* o = out + (size_t)n*HC + jg;
  o[0]=a0; o[1]=a1; o[2]=a2; o[3]=a3;
}

// ---------------- GAT edge scatter: out[d,colOff+f] += e_h * hs[s,f]; z[d,h] += e_h ----------------
__global__ void k_gat_edge(const int* __restrict__ src, const int* __restrict__ dst,
                           int E, int nloop,
                           const float* __restrict__ hs,
                           const float* __restrict__ als, const float* __restrict__ ald,
                           float* __restrict__ z, float* __restrict__ outcat, int colOff){
  int i = blockIdx.x*blockDim.x + threadIdx.x;
  int total = (E+nloop)*HC;
  if(i>=total) return;
  int e = i/HC, f = i%HC;
  int s, d;
  if(e<E){ s = src[e]; d = dst[e]; } else { s = d = e-E; }
  int h = f/CD;
  float lg = als[s*2+h] + ald[d*2+h];
  lg = lg>0.f ? lg : 0.2f*lg;           // leaky_relu(0.2)
  float ev = __expf(lg);
  if(f==0)  atomicAdd(&z[d*2+0], ev);
  if(f==CD) atomicAdd(&z[d*2+1], ev);
  atomicAdd(&outcat[(size_t)d*DF + colOff + f], ev*hs[(size_t)s*HC + f]);
}

// ---------------- finalize GAT concat: divide by softmax denom, add biases ----------------
__global__ void k_gat_fin(float* __restrict__ cat, const float* __restrict__ zA, const float* __restrict__ zB,
                          const float* __restrict__ bA, const float* __restrict__ bB, int N){
  int i = blockIdx.x*blockDim.x + threadIdx.x;
  if(i>=N*DF) return;
  int n = i/DF, f = i%DF;
  float v = cat[i];
  if(f<HC){
    int h = f/CD;
    v = v/(zA[n*2+h]+1e-16f) + bA[f];
  } else {
    int f2 = f-HC; int h = f2/CD;
    v = v/(zB[n*2+h]+1e-16f) + bB[f2];
  }
  cat[i] = v;
}

// ---------------- graph layernorm stats (one wave per node) ----------------
__global__ void k_ln_stats(const float* __restrict__ x, const int* __restrict__ batch,
                           float* __restrict__ gs, float* __restrict__ gq, float* __restrict__ gc, int N){
  int n = blockIdx.x; if(n>=N) return;
  int lane = threadIdx.x;
  float s=0.f, q=0.f;
  const float* xr = x + (size_t)n*DF;
  for(int f=lane; f<DF; f+=64){ float v = xr[f]; s += v; q += v*v; }
  for(int o=32;o;o>>=1){ s += __shfl_down(s,o); q += __shfl_down(q,o); }
  if(lane==0){
    int g = batch[n];
    atomicAdd(&gs[g], s); atomicAdd(&gq[g], q); atomicAdd(&gc[g], 1.0f);
  }
}

// ---------------- graph layernorm normalize + elu (in place) ----------------
__global__ void k_ln_norm(float* __restrict__ x, const int* __restrict__ batch,
                          const float* __restrict__ gs, const float* __restrict__ gq, const float* __restrict__ gc,
                          const float* __restrict__ wv, const float* __restrict__ bv, int N){
  int i = blockIdx.x*blockDim.x + threadIdx.x;
  if(i>=N*DF) return;
  int n = i/DF, f = i%DF, g = batch[n];
  float norm = fmaxf(gc[g],1.f)*(float)DF;
  float mean = gs[g]/norm;
  float var  = fmaxf(gq[g]/norm - mean*mean, 0.f);
  float v = (x[i]-mean)*rsqrtf(var+1e-5f)*wv[f] + bv[f];
  x[i] = eluf(v);
}

// ---------------- SAG: sagg[dst] += yrel[src] ----------------
__global__ void k_sag_edge(const int* __restrict__ src, const int* __restrict__ dst, int E,
                           const float* __restrict__ y2, float* __restrict__ sagg){
  int e = blockIdx.x*blockDim.x + threadIdx.x;
  if(e<E) atomicAdd(&sagg[dst[e]], y2[src[e]*2]);
}

// ---------------- SAG: en[n]=exp(score); zg[g]+=en ----------------
__global__ void k_sag_exp(const float* __restrict__ sagg, const float* __restrict__ y2,
                          const float* __restrict__ brel,
                          float* __restrict__ en, float* __restrict__ zg,
                          const int* __restrict__ batch, int N){
  int n = blockIdx.x*blockDim.x + threadIdx.x;
  if(n>=N) return;
  float sc = sagg[n] + brel[0] + y2[n*2+1];
  float e = __expf(sc);
  en[n] = e;
  atomicAdd(&zg[batch[n]], e);
}

// ---------------- SAG: out = x * alpha (f32 store to d_out) ----------------
__global__ void k_sag_out(const float* __restrict__ x, const float* __restrict__ en,
                          const float* __restrict__ zg, const int* __restrict__ batch,
                          float* __restrict__ out, int N){
  int i = blockIdx.x*blockDim.x + threadIdx.x;
  if(i>=N*DF) return;
  int n = i/DF;
  float a = en[n]/(zg[batch[n]]+1e-16f);
  out[i] = x[i]*a;
}

// ---------------- per-graph readout: outg[g,f] = (sum_n x[n,f]*en[n]) / zg[g] ----------------
__global__ void k_graph_sum(const float* __restrict__ x, const float* __restrict__ en,
                            const float* __restrict__ zg, const int* __restrict__ batch,
                            float* __restrict__ outg, int N){
  int g = blockIdx.x;
  int lo=0, hi=N;
  while(lo<hi){ int m=(lo+hi)>>1; if(batch[m]<g) lo=m+1; else hi=m; }
  int start = lo;
  hi = N;
  while(lo<hi){ int m=(lo+hi)>>1; if(batch[m]<g+1) lo=m+1; else hi=m; }
  int end = lo;
  int f = threadIdx.x;
  if(f>=DF) return;
  float s = 0.f;
  for(int n=start;n<end;n++) s += x[(size_t)n*DF+f]*en[n];
  outg[(size_t)g*DF+f] = s/(zg[g]+1e-16f);
}

extern "C" void kernel_launch(void* const* d_in, const int* in_sizes, int n_in,
                              void* d_out, int out_size, void* d_ws, size_t ws_size,
                              hipStream_t stream){
  const float* atom_x    = (const float*)d_in[0];
  const int*   atom_ei   = (const int*)  d_in[1];
  const int*   atom_batch= (const int*)  d_in[2];
  const float* aa_x      = (const float*)d_in[3];
  const int*   aa_ei     = (const int*)  d_in[4];
  /* d_in[5] aa_edge_attr: ignored (GATConv has no edge_dim) */
  const int*   aa_batch  = (const int*)  d_in[6];
  const int*   m2p       = (const int*)  d_in[7];
  const float* Wd     =(const float*)d_in[8];
  const float* ad_src =(const float*)d_in[9];
  const float* ad_dst =(const float*)d_in[10];
  const float* bd     =(const float*)d_in[11];
  const float* Wp     =(const float*)d_in[12];
  const float* ap_src =(const float*)d_in[13];
  const float* ap_dst =(const float*)d_in[14];
  const float* bp     =(const float*)d_in[15];
  const float* Wi_src =(const float*)d_in[16];
  const float* Wi_dst =(const float*)d_in[17];
  const float* ai_src =(const float*)d_in[18];
  const float* ai_dst =(const float*)d_in[19];
  const float* bi     =(const float*)d_in[20];
  const float* ln_d_w =(const float*)d_in[21];
  const float* ln_d_b =(const float*)d_in[22];
  const float* ln_p_w =(const float*)d_in[23];
  const float* ln_p_b =(const float*)d_in[24];
  const float* pd_Wrel=(const float*)d_in[25];
  const float* pd_brel=(const float*)d_in[26];
  const float* pd_Wroot=(const float*)d_in[27];
  const float* pp_Wrel=(const float*)d_in[28];
  const float* pp_brel=(const float*)d_in[29];
  const float* pp_Wroot=(const float*)d_in[30];

  const int nA = in_sizes[0]/DF;     // 25600 atoms
  const int EA = in_sizes[1]/2;      // 102400 atom edges
  const int nP = in_sizes[3]/DF;     // 204800 aa nodes
  const int EP = in_sizes[4]/2;      // 1024000 aa edges
  const int EM = in_sizes[7]/2;      // 512000 m2p edges
  const int nLoop = nA<nP ? nA : nP;

  float* w = (float*)d_ws;
  size_t off = 0;
  auto alloc = [&](size_t n){ float* p = w+off; off += (n+63)&~(size_t)63; return p; };

  float* AX  = alloc((size_t)nA*DF);   // elu(atom_x) -> atom_cat -> atom_h
  float* AB  = alloc((size_t)nP*DF);   // elu(aa_x)   -> aa_cat   -> aa_h
  float* H1  = alloc((size_t)nA*HC);   // h1 (atom@Wd), later hs4 (atom_h@Wi_src)
  float* HS2 = alloc((size_t)nP*HC);   // aa@Wi_src
  float* H3  = alloc((size_t)nP*HC);   // aa@Wp
  float* als1=alloc((size_t)nA*2); float* ald1=alloc((size_t)nA*2);
  float* als2=alloc((size_t)nP*2); float* ald2=alloc((size_t)nA*2);
  float* als3=alloc((size_t)nP*2); float* ald3=alloc((size_t)nP*2);
  float* als4=alloc((size_t)nA*2); float* ald4=alloc((size_t)nP*2);
  float* Vds=alloc(DF*2); float* Vdd=alloc(DF*2);
  float* Vps=alloc(DF*2); float* Vpd=alloc(DF*2);
  float* Vis=alloc(DF*2); float* Vid=alloc(DF*2);
  float* VsA=alloc(DF*2); float* VsP=alloc(DF*2);
  float* y2A=alloc((size_t)nA*2); float* y2P=alloc((size_t)nP*2);
  float* enA=alloc(nA);   float* enP=alloc(nP);
  // ---- contiguous zero region ----
  float* zr0 = w+off;
  float* z1=alloc((size_t)nA*2); float* z2=alloc((size_t)nA*2);
  float* z3=alloc((size_t)nP*2); float* z4=alloc((size_t)nP*2);
  float* gsA=alloc(NG); float* gqA=alloc(NG); float* gcA=alloc(NG);
  float* gsP=alloc(NG); float* gqP=alloc(NG); float* gcP=alloc(NG);
  float* saggA=alloc(nA); float* saggP=alloc(nP);
  float* zgA=alloc(NG); float* zgP=alloc(NG);
  size_t zrBytes = ((w+off) - zr0)*sizeof(float);
  if(off*sizeof(float) > ws_size) return; // workspace too small — bail

  float* out_atom = (float*)d_out;
  float* out_aa   = out_atom + (size_t)nA*DF;
  float* out_dg   = out_aa   + (size_t)nP*DF;
  float* out_pg   = out_dg   + (size_t)NG*DF;

  const int B = 256;
  hipMemsetAsync(zr0, 0, zrBytes, stream);

  // 1. elu
  k_elu<<<(nA*DF+B-1)/B, B, 0, stream>>>(atom_x, AX, nA*DF);
  k_elu<<<(nP*DF+B-1)/B, B, 0, stream>>>(aa_x,   AB, nP*DF);

  // 2. fused attention vectors
  k_makeV<<<2,B,0,stream>>>(Wd,     ad_src, Vds);
  k_makeV<<<2,B,0,stream>>>(Wd,     ad_dst, Vdd);
  k_makeV<<<2,B,0,stream>>>(Wp,     ap_src, Vps);
  k_makeV<<<2,B,0,stream>>>(Wp,     ap_dst, Vpd);
  k_makeV<<<2,B,0,stream>>>(Wi_src, ai_src, Vis);
  k_makeV<<<2,B,0,stream>>>(Wi_dst, ai_dst, Vid);
  k_pack2<<<1,B,0,stream>>>(pd_Wrel, pd_Wroot, VsA);
  k_pack2<<<1,B,0,stream>>>(pp_Wrel, pp_Wroot, VsP);

  // 3. GEMMs + attention GEMVs (consume elu buffers)
  k_gemm<<<(nA*25+B-1)/B, B, 0, stream>>>(AX, Wd,     H1,  nA);
  k_gemm<<<(nP*25+B-1)/B, B, 0, stream>>>(AB, Wi_src, HS2, nP);
  k_gemm<<<(nP*25+B-1)/B, B, 0, stream>>>(AB, Wp,     H3,  nP);
  k_gemv2<<<nA,64,0,stream>>>(AX, Vds, als1, nA);
  k_gemv2<<<nA,64,0,stream>>>(AX, Vdd, ald1, nA);
  k_gemv2<<<nP,64,0,stream>>>(AB, Vis, als2, nP);
  k_gemv2<<<nA,64,0,stream>>>(AX, Vid, ald2, nA);
  k_gemv2<<<nP,64,0,stream>>>(AB, Vps, als3, nP);
  k_gemv2<<<nP,64,0,stream>>>(AB, Vpd, ald3, nP);
  k_gemv2<<<nP,64,0,stream>>>(AB, Vid, ald4, nP);

  // 4. zero cat accumulators (reuse AX/AB), scatter GAT1/GAT2/GAT3
  hipMemsetAsync(AX, 0, (size_t)nA*DF*sizeof(float), stream);
  hipMemsetAsync(AB, 0, (size_t)nP*DF*sizeof(float), stream);
  { int tot=(EA+nA)*HC;
    k_gat_edge<<<(tot+B-1)/B,B,0,stream>>>(atom_ei, atom_ei+EA, EA, nA, H1, als1, ald1, z1, AX, 0); }
  { int tot=(EM+nLoop)*HC;  // atom_inter: src=aa(m2p row1), dst=atom(m2p row0)
    k_gat_edge<<<(tot+B-1)/B,B,0,stream>>>(m2p+EM, m2p, EM, nLoop, HS2, als2, ald2, z2, AX, HC); }
  { int tot=(EP+nP)*HC;
    k_gat_edge<<<(tot+B-1)/B,B,0,stream>>>(aa_ei, aa_ei+EP, EP, nP, H3, als3, ald3, z3, AB, 0); }

  // 5. atom: finalize + graph-LN + elu  -> atom_h (in AX)
  k_gat_fin<<<(nA*DF+B-1)/B,B,0,stream>>>(AX, z1, z2, bd, bi, nA);
  k_ln_stats<<<nA,64,0,stream>>>(AX, atom_batch, gsA, gqA, gcA, nA);
  k_ln_norm<<<(nA*DF+B-1)/B,B,0,stream>>>(AX, atom_batch, gsA, gqA, gcA, ln_d_w, ln_d_b, nA);

  // 6. hs4 = atom_h @ Wi_src (reuse H1), als4; GAT4 scatter
  k_gemm<<<(nA*25+B-1)/B, B, 0, stream>>>(AX, Wi_src, H1, nA);
  k_gemv2<<<nA,64,0,stream>>>(AX, Vis, als4, nA);
  { int tot=(EM+nLoop)*HC;  // aa_inter: src=atom(m2p row0), dst=aa(m2p row1)
    k_gat_edge<<<(tot+B-1)/B,B,0,stream>>>(m2p, m2p+EM, EM, nLoop, H1, als4, ald4, z4, AB, HC); }

  // 7. aa: finalize + graph-LN + elu -> aa_h (in AB)
  k_gat_fin<<<(nP*DF+B-1)/B,B,0,stream>>>(AB, z3, z4, bp, bi, nP);
  k_ln_stats<<<nP,64,0,stream>>>(AB, aa_batch, gsP, gqP, gcP, nP);
  k_ln_norm<<<(nP*DF+B-1)/B,B,0,stream>>>(AB, aa_batch, gsP, gqP, gcP, ln_p_w, ln_p_b, nP);

  // 8. SAG pool atom + readout
  k_gemv2<<<nA,64,0,stream>>>(AX, VsA, y2A, nA);
  k_sag_edge<<<(EA+B-1)/B,B,0,stream>>>(atom_ei, atom_ei+EA, EA, y2A, saggA);
  k_sag_exp<<<(nA+B-1)/B,B,0,stream>>>(saggA, y2A, pd_brel, enA, zgA, atom_batch, nA);
  k_sag_out<<<(nA*DF+B-1)/B,B,0,stream>>>(AX, enA, zgA, atom_batch, out_atom, nA);
  k_graph_sum<<<NG,B,0,stream>>>(AX, enA, zgA, atom_batch, out_dg, nA);

  // 9. SAG pool aa + readout
  k_gemv2<<<nP,64,0,stream>>>(AB, VsP, y2P, nP);
  k_sag_edge<<<(EP+B-1)/B,B,0,stream>>>(aa_ei, aa_ei+EP, EP, y2P, saggP);
  k_sag_exp<<<(nP+B-1)/B,B,0,stream>>>(saggP, y2P, pp_brel, enP, zgP, aa_batch, nP);
  k_sag_out<<<(nP*DF+B-1)/B,B,0,stream>>>(AB, enP, zgP, aa_batch, out_aa, nP);
  k_graph_sum<<<NG,B,0,stream>>>(AB, enP, zgP, aa_batch, out_pg, nP);
}